// Round 5
// baseline (270.234 us; speedup 1.0000x reference)
//
#include <hip/hip_runtime.h>

#define BATCH 64
#define DIM 256
#define HW 1024
#define N_POS 65536
#define K_CODES 1024
#define NTOT 16777216

typedef __bf16 bf16x8 __attribute__((ext_vector_type(8)));
typedef float f32x4 __attribute__((ext_vector_type(4)));

__device__ inline unsigned short f2bf(float f) {
    unsigned int u = __builtin_bit_cast(unsigned int, f);
    unsigned int r = u + 0x7FFFu + ((u >> 16) & 1u);
    return (unsigned short)(r >> 16);
}
__device__ inline float bf2f(unsigned short u) {
    unsigned int x = ((unsigned int)u) << 16;
    return __builtin_bit_cast(float, x);
}
__device__ inline unsigned umax2(unsigned a, unsigned b) { return a > b ? a : b; }

// ---------------------------------------------------------------------------
// Kernel 0: cbt[k][d] = bf16(cb[k][d]); cnorm[k] = 0.5*||bf16(c_k)||^2
__global__ void cbprep_kernel(const float* __restrict__ cb, unsigned short* __restrict__ cbt,
                              float* __restrict__ cnorm) {
    const int wv = threadIdx.x >> 6, lane = threadIdx.x & 63;
    const int k = blockIdx.x * 4 + wv;                 // grid 256
    const float4 v = *reinterpret_cast<const float4*>(cb + (size_t)k * DIM + lane * 4);
    ushort4 pk;
    pk.x = f2bf(v.x); pk.y = f2bf(v.y); pk.z = f2bf(v.z); pk.w = f2bf(v.w);
    *reinterpret_cast<ushort4*>(cbt + (size_t)k * DIM + lane * 4) = pk;
    const float f0 = bf2f(pk.x), f1 = bf2f(pk.y), f2 = bf2f(pk.z), f3 = bf2f(pk.w);
    float s = f0 * f0 + f1 * f1 + f2 * f2 + f3 * f3;
    #pragma unroll
    for (int off = 32; off; off >>= 1) s += __shfl_xor(s, off);
    if (lane == 0) cnorm[k] = 0.5f * s;
}

// ---------------------------------------------------------------------------
// Kernel 1: transpose+convert: xt[b*1024+p][d] = bf16(x[b][d][p])
__global__ __launch_bounds__(256) void transpose_kernel(
        const float* __restrict__ x, unsigned short* __restrict__ xt) {
    __shared__ unsigned char ts[64 * 512];
    const int tid = threadIdx.x;
    const int b  = blockIdx.x >> 4;                    // grid 1024
    const int p0 = (blockIdx.x & 15) << 6;
    const float* xb = x + (size_t)b * (DIM * HW) + p0;
    const int p4 = tid & 15;
    const int dh = tid >> 4;
    #pragma unroll
    for (int dp = 0; dp < 8; ++dp) {
        const int d0 = dp * 32 + dh * 2;
        const float4 v0 = *reinterpret_cast<const float4*>(xb + (size_t)d0 * HW + p4 * 4);
        const float4 v1 = *reinterpret_cast<const float4*>(xb + (size_t)(d0 + 1) * HW + p4 * 4);
        const float a0[4] = {v0.x, v0.y, v0.z, v0.w};
        const float a1[4] = {v1.x, v1.y, v1.z, v1.w};
        #pragma unroll
        for (int e = 0; e < 4; ++e) {
            const int p = p4 * 4 + e;
            const unsigned int pk = (unsigned int)f2bf(a0[e]) | ((unsigned int)f2bf(a1[e]) << 16);
            const int col = (d0 * 2) ^ ((p & 7) << 4);
            *reinterpret_cast<unsigned int*>(&ts[p * 512 + col]) = pk;
        }
    }
    __syncthreads();
    const int ck = tid & 31;
    const int pr = tid >> 5;
    unsigned char* xt8 = (unsigned char*)xt;
    #pragma unroll
    for (int pp = 0; pp < 8; ++pp) {
        const int p = pp * 8 + pr;
        const uint4 v = *reinterpret_cast<const uint4*>(&ts[p * 512 + ((ck * 16) ^ ((p & 7) << 4))]);
        *reinterpret_cast<uint4*>(xt8 + (((size_t)(b * HW + p0 + p)) << 9) + ck * 16) = v;
    }
}

// ---------------------------------------------------------------------------
// Kernel 2: MFMA scoring + fused packed argmin (R4 algorithm, register-fitted).
// 4 waves; wave w owns codes [w*256, w*256+256) over all 128 positions.
// score' = 1 - cnorm[k] + dot (cnorm folded into C-init). Packed best:
// p = (bits(score') & ~1023) | (1023-k); u32-max == score-max, ties -> min k.
__global__ __launch_bounds__(256, 2) void score_kernel(
        const unsigned short* __restrict__ xt, const unsigned short* __restrict__ cbt,
        const float* __restrict__ cnorm, int* __restrict__ idx_out) {
    __shared__ unsigned char xs[64 * 1024];            // 128 pos x 512B
    const int tid = threadIdx.x;
    const int l = tid & 63, w = tid >> 6;
    const int n0 = blockIdx.x * 128;                   // grid 512
    const unsigned char* cbt8 = (const unsigned char*)cbt;

    {   // stage x tile via global_load_lds, pre-swizzled source
        const unsigned char* xt8 = (const unsigned char*)xt;
        #pragma unroll
        for (int it = 0; it < 16; ++it) {
            const int X = w * 1024 + it * 4096 + l * 16;
            const int pos = X >> 9, col = X & 511;
            const unsigned char* src = xt8 + ((size_t)(n0 + pos) << 9) + (col ^ ((pos & 7) << 4));
            __builtin_amdgcn_global_load_lds(
                (const __attribute__((address_space(1))) void*)src,
                (__attribute__((address_space(3))) void*)(&xs[w * 1024 + it * 4096]),
                16, 0, 0);
        }
    }
    __syncthreads();

    const int g = l >> 4, ln = l & 15;

    unsigned bestp[32];                                // slot (mf,r) = mf*4+r
    #pragma unroll
    for (int i = 0; i < 32; ++i) bestp[i] = 0u;

    #pragma unroll 1
    for (int kt = 0; kt < 4; ++kt) {
        const int c0 = w * 256 + kt * 64;
        float adj[4];
        #pragma unroll
        for (int nf = 0; nf < 4; ++nf)
            adj[nf] = 1.0f - cnorm[c0 + nf * 16 + ln];

        f32x4 acc[8][4];
        #pragma unroll
        for (int mf = 0; mf < 8; ++mf)
            #pragma unroll
            for (int nf = 0; nf < 4; ++nf)
                acc[mf][nf] = (f32x4){adj[nf], adj[nf], adj[nf], adj[nf]};

        bf16x8 bb[2][4];                               // ping-pong B fragments
        #pragma unroll
        for (int nf = 0; nf < 4; ++nf)
            bb[0][nf] = *reinterpret_cast<const bf16x8*>(
                cbt8 + ((size_t)(c0 + nf * 16 + ln) << 9) + g * 16);

        #pragma unroll
        for (int kk = 0; kk < 8; ++kk) {
            const int cur = kk & 1, nxt = cur ^ 1;     // compile-time under full unroll
            if (kk < 7) {
                #pragma unroll
                for (int nf = 0; nf < 4; ++nf)
                    bb[nxt][nf] = *reinterpret_cast<const bf16x8*>(
                        cbt8 + ((size_t)(c0 + nf * 16 + ln) << 9) + (kk + 1) * 64 + g * 16);
            }
            #pragma unroll
            for (int mf = 0; mf < 8; ++mf) {           // A loaded just-in-time per mf
                const int pos = mf * 16 + ln;
                const bf16x8 a = *reinterpret_cast<const bf16x8*>(
                    &xs[pos * 512 + ((kk * 64 + g * 16) ^ ((ln & 7) << 4))]);
                #pragma unroll
                for (int nf = 0; nf < 4; ++nf)
                    acc[mf][nf] = __builtin_amdgcn_mfma_f32_16x16x32_bf16(
                        a, bb[cur][nf], acc[mf][nf], 0, 0, 0);
            }
        }

        // epilogue: packed score|idx, u32-max (iv recomputed, not carried)
        #pragma unroll
        for (int mf = 0; mf < 8; ++mf)
            #pragma unroll
            for (int r = 0; r < 4; ++r) {
                unsigned c[4];
                #pragma unroll
                for (int nf = 0; nf < 4; ++nf) {
                    const unsigned iv = (unsigned)(1023 - (c0 + nf * 16 + ln));
                    c[nf] = (__builtin_bit_cast(unsigned, acc[mf][nf][r]) & 0xFFFFFC00u) | iv;
                }
                bestp[mf * 4 + r] = umax2(bestp[mf * 4 + r],
                                          umax2(umax2(c[0], c[1]), umax2(c[2], c[3])));
            }
    }

    // reduce over ln (16 lanes per g-group share positions, hold disjoint codes)
    #pragma unroll
    for (int off = 1; off < 16; off <<= 1) {
        #pragma unroll
        for (int s = 0; s < 32; ++s)
            bestp[s] = umax2(bestp[s], (unsigned)__shfl_xor((int)bestp[s], off));
    }

    // merge 4 waves via LDS atomicMax, then decode
    __syncthreads();                                   // xs reads done
    unsigned* merged = (unsigned*)xs;
    if (tid < 128) merged[tid] = 0u;
    __syncthreads();
    if (ln == 0) {
        #pragma unroll
        for (int mf = 0; mf < 8; ++mf)
            #pragma unroll
            for (int r = 0; r < 4; ++r)
                atomicMax(&merged[mf * 16 + g * 4 + r], bestp[mf * 4 + r]);
    }
    __syncthreads();
    if (tid < 128) idx_out[n0 + tid] = 1023 - (int)(merged[tid] & 1023u);
}

// ---------------------------------------------------------------------------
// Kernel 3: gather + quantize + fused (x-q)^2 partials. float4 over p.
__global__ __launch_bounds__(256) void quantize_kernel(
        const float* __restrict__ x, const float* __restrict__ cb,
        const int* __restrict__ idx, float* __restrict__ out,
        float* __restrict__ partial) {
    const int blk = blockIdx.x;
    const int b  = blk >> 2;
    const int d0 = (blk & 3) * 64;
    const int tid = threadIdx.x;
    const int4 ci = *reinterpret_cast<const int4*>(&idx[b * HW + tid * 4]);
    const int cia[4] = {ci.x, ci.y, ci.z, ci.w};
    const size_t xbase = (size_t)b * (DIM * HW) + tid * 4;

    float s = 0.0f;
    #pragma unroll 4
    for (int dq = 0; dq < 16; ++dq) {
        const int dd = d0 + dq * 4;
        float4 xv[4], cv[4];
        #pragma unroll
        for (int j = 0; j < 4; ++j)
            xv[j] = *reinterpret_cast<const float4*>(&x[xbase + (size_t)(dd + j) * HW]);
        #pragma unroll
        for (int e = 0; e < 4; ++e)
            cv[e] = *reinterpret_cast<const float4*>(&cb[(size_t)cia[e] * DIM + dd]);
        #pragma unroll
        for (int j = 0; j < 4; ++j) {
            const float q0 = (&cv[0].x)[j], q1 = (&cv[1].x)[j],
                        q2 = (&cv[2].x)[j], q3 = (&cv[3].x)[j];
            float4 ov = {q0, q1, q2, q3};
            *reinterpret_cast<float4*>(&out[xbase + (size_t)(dd + j) * HW]) = ov;
            const float e0 = xv[j].x - q0, e1 = xv[j].y - q1,
                        e2 = xv[j].z - q2, e3 = xv[j].w - q3;
            s = fmaf(e0, e0, s); s = fmaf(e1, e1, s);
            s = fmaf(e2, e2, s); s = fmaf(e3, e3, s);
        }
    }
    #pragma unroll
    for (int off = 32; off; off >>= 1) s += __shfl_xor(s, off);
    __shared__ float wsum[4];
    if ((tid & 63) == 0) wsum[tid >> 6] = s;
    __syncthreads();
    if (tid == 0) partial[blk] = wsum[0] + wsum[1] + wsum[2] + wsum[3];
}

// ---------------------------------------------------------------------------
__global__ void finalize_kernel(const float* __restrict__ partial, float* __restrict__ out_loss) {
    float s = (threadIdx.x < 256) ? partial[threadIdx.x] : 0.0f;
    #pragma unroll
    for (int off = 32; off; off >>= 1) s += __shfl_xor(s, off);
    __shared__ float wsum[4];
    if ((threadIdx.x & 63) == 0) wsum[threadIdx.x >> 6] = s;
    __syncthreads();
    if (threadIdx.x == 0)
        out_loss[0] = 1.25f * (wsum[0] + wsum[1] + wsum[2] + wsum[3]) / (float)NTOT;
}

// ---------------------------------------------------------------------------
extern "C" void kernel_launch(void* const* d_in, const int* in_sizes, int n_in,
                              void* d_out, int out_size, void* d_ws, size_t ws_size,
                              hipStream_t stream) {
    const float* x  = (const float*)d_in[0];   // [64,256,32,32]
    const float* cb = (const float*)d_in[1];   // [1024,256]
    float* out = (float*)d_out;                // [16777216] + [1 loss]

    // xt (32 MB) + cbt (512 KB) live in d_out; quantize overwrites later.
    unsigned short* xt  = (unsigned short*)d_out;
    unsigned short* cbt = xt + (size_t)N_POS * DIM;
    // ws: idx[65536] ints | partial[256] f32 | cnorm[1024] f32
    int*   idx     = (int*)d_ws;
    float* partial = (float*)((char*)d_ws + 262144);
    float* cnorm   = (float*)((char*)d_ws + 262144 + 4096);

    cbprep_kernel   <<<dim3(256),  dim3(256), 0, stream>>>(cb, cbt, cnorm);
    transpose_kernel<<<dim3(1024), dim3(256), 0, stream>>>(x, xt);
    score_kernel    <<<dim3(512),  dim3(256), 0, stream>>>(xt, cbt, cnorm, idx);
    quantize_kernel <<<dim3(256),  dim3(256), 0, stream>>>(x, cb, idx, out, partial);
    finalize_kernel <<<dim3(1),    dim3(256), 0, stream>>>(partial, out + NTOT);
}

// Round 6
// 214.680 us; speedup vs baseline: 1.2588x; 1.2588x over previous
//
#include <hip/hip_runtime.h>

#define BATCH 64
#define DIM 256
#define HW 1024
#define N_POS 65536
#define K_CODES 1024
#define NTOT 16777216

typedef __bf16 bf16x8 __attribute__((ext_vector_type(8)));
typedef float f32x4 __attribute__((ext_vector_type(4)));

__device__ inline unsigned short f2bf(float f) {
    unsigned int u = __builtin_bit_cast(unsigned int, f);
    unsigned int r = u + 0x7FFFu + ((u >> 16) & 1u);
    return (unsigned short)(r >> 16);
}
__device__ inline float bf2f(unsigned short u) {
    unsigned int x = ((unsigned int)u) << 16;
    return __builtin_bit_cast(float, x);
}
__device__ inline unsigned umax2(unsigned a, unsigned b) { return a > b ? a : b; }

// ---------------------------------------------------------------------------
// Kernel 0: cbt[k][d] = bf16(cb[k][d]); cnorm[k] = 0.5*||bf16(c_k)||^2
__global__ void cbprep_kernel(const float* __restrict__ cb, unsigned short* __restrict__ cbt,
                              float* __restrict__ cnorm) {
    const int wv = threadIdx.x >> 6, lane = threadIdx.x & 63;
    const int k = blockIdx.x * 4 + wv;                 // grid 256
    const float4 v = *reinterpret_cast<const float4*>(cb + (size_t)k * DIM + lane * 4);
    ushort4 pk;
    pk.x = f2bf(v.x); pk.y = f2bf(v.y); pk.z = f2bf(v.z); pk.w = f2bf(v.w);
    *reinterpret_cast<ushort4*>(cbt + (size_t)k * DIM + lane * 4) = pk;
    const float f0 = bf2f(pk.x), f1 = bf2f(pk.y), f2 = bf2f(pk.z), f3 = bf2f(pk.w);
    float s = f0 * f0 + f1 * f1 + f2 * f2 + f3 * f3;
    #pragma unroll
    for (int off = 32; off; off >>= 1) s += __shfl_xor(s, off);
    if (lane == 0) cnorm[k] = 0.5f * s;
}

// ---------------------------------------------------------------------------
// Kernel 1: transpose+convert: xt[b*1024+p][d] = bf16(x[b][d][p])
__global__ __launch_bounds__(256) void transpose_kernel(
        const float* __restrict__ x, unsigned short* __restrict__ xt) {
    __shared__ unsigned char ts[64 * 512];
    const int tid = threadIdx.x;
    const int b  = blockIdx.x >> 4;                    // grid 1024
    const int p0 = (blockIdx.x & 15) << 6;
    const float* xb = x + (size_t)b * (DIM * HW) + p0;
    const int p4 = tid & 15;
    const int dh = tid >> 4;
    #pragma unroll
    for (int dp = 0; dp < 8; ++dp) {
        const int d0 = dp * 32 + dh * 2;
        const float4 v0 = *reinterpret_cast<const float4*>(xb + (size_t)d0 * HW + p4 * 4);
        const float4 v1 = *reinterpret_cast<const float4*>(xb + (size_t)(d0 + 1) * HW + p4 * 4);
        const float a0[4] = {v0.x, v0.y, v0.z, v0.w};
        const float a1[4] = {v1.x, v1.y, v1.z, v1.w};
        #pragma unroll
        for (int e = 0; e < 4; ++e) {
            const int p = p4 * 4 + e;
            const unsigned int pk = (unsigned int)f2bf(a0[e]) | ((unsigned int)f2bf(a1[e]) << 16);
            const int col = (d0 * 2) ^ ((p & 7) << 4);
            *reinterpret_cast<unsigned int*>(&ts[p * 512 + col]) = pk;
        }
    }
    __syncthreads();
    const int ck = tid & 31;
    const int pr = tid >> 5;
    unsigned char* xt8 = (unsigned char*)xt;
    #pragma unroll
    for (int pp = 0; pp < 8; ++pp) {
        const int p = pp * 8 + pr;
        const uint4 v = *reinterpret_cast<const uint4*>(&ts[p * 512 + ((ck * 16) ^ ((p & 7) << 4))]);
        *reinterpret_cast<uint4*>(xt8 + (((size_t)(b * HW + p0 + p)) << 9) + ck * 16) = v;
    }
}

// ---------------------------------------------------------------------------
// Kernel 2: MFMA scoring + fused packed argmin.
// __launch_bounds__(256,1): 512-reg budget -> acc[8][4] + bB[8][4] fit with NO
// spill (R4/R5 spilled at the 256-reg cap). 1 wave/SIMD; steady state is
// MFMA-bound within the wave (4 MFMA per ds_read_b128). All 32 B-loads of a
// kt are issued upfront so L2 latency is paid once per kt.
__global__ __launch_bounds__(256, 1) void score_kernel(
        const unsigned short* __restrict__ xt, const unsigned short* __restrict__ cbt,
        const float* __restrict__ cnorm, int* __restrict__ idx_out) {
    __shared__ unsigned char xs[64 * 1024];            // 128 pos x 512B
    const int tid = threadIdx.x;
    const int l = tid & 63, w = tid >> 6;
    const int n0 = blockIdx.x * 128;                   // grid 512
    const unsigned char* cbt8 = (const unsigned char*)cbt;

    {   // stage x tile via global_load_lds, pre-swizzled source
        const unsigned char* xt8 = (const unsigned char*)xt;
        #pragma unroll
        for (int it = 0; it < 16; ++it) {
            const int X = w * 1024 + it * 4096 + l * 16;
            const int pos = X >> 9, col = X & 511;
            const unsigned char* src = xt8 + ((size_t)(n0 + pos) << 9) + (col ^ ((pos & 7) << 4));
            __builtin_amdgcn_global_load_lds(
                (const __attribute__((address_space(1))) void*)src,
                (__attribute__((address_space(3))) void*)(&xs[w * 1024 + it * 4096]),
                16, 0, 0);
        }
    }
    __syncthreads();

    const int g = l >> 4, ln = l & 15;

    unsigned bestp[32];                                // slot (mf,r) = mf*4+r
    #pragma unroll
    for (int i = 0; i < 32; ++i) bestp[i] = 0u;

    #pragma unroll 1
    for (int kt = 0; kt < 4; ++kt) {
        const int c0 = w * 256 + kt * 64;
        float adj[4];
        #pragma unroll
        for (int nf = 0; nf < 4; ++nf)
            adj[nf] = 1.0f - cnorm[c0 + nf * 16 + ln];

        f32x4 acc[8][4];
        #pragma unroll
        for (int mf = 0; mf < 8; ++mf)
            #pragma unroll
            for (int nf = 0; nf < 4; ++nf)
                acc[mf][nf] = (f32x4){adj[nf], adj[nf], adj[nf], adj[nf]};

        // issue ALL B-loads for this kt (one L2-latency wait per kt)
        bf16x8 bB[8][4];
        #pragma unroll
        for (int kk = 0; kk < 8; ++kk)
            #pragma unroll
            for (int nf = 0; nf < 4; ++nf)
                bB[kk][nf] = *reinterpret_cast<const bf16x8*>(
                    cbt8 + ((size_t)(c0 + nf * 16 + ln) << 9) + kk * 64 + g * 16);

        #pragma unroll
        for (int kk = 0; kk < 8; ++kk) {
            #pragma unroll
            for (int mf = 0; mf < 8; ++mf) {           // A loaded just-in-time per mf
                const int pos = mf * 16 + ln;
                const bf16x8 a = *reinterpret_cast<const bf16x8*>(
                    &xs[pos * 512 + ((kk * 64 + g * 16) ^ ((ln & 7) << 4))]);
                #pragma unroll
                for (int nf = 0; nf < 4; ++nf)
                    acc[mf][nf] = __builtin_amdgcn_mfma_f32_16x16x32_bf16(
                        a, bB[kk][nf], acc[mf][nf], 0, 0, 0);
            }
        }

        // epilogue: packed score|idx, u32-max: (bits(score)&~1023)|(1023-k)
        #pragma unroll
        for (int mf = 0; mf < 8; ++mf)
            #pragma unroll
            for (int r = 0; r < 4; ++r) {
                unsigned c[4];
                #pragma unroll
                for (int nf = 0; nf < 4; ++nf) {
                    const unsigned iv = (unsigned)(1023 - (c0 + nf * 16 + ln));
                    c[nf] = (__builtin_bit_cast(unsigned, acc[mf][nf][r]) & 0xFFFFFC00u) | iv;
                }
                bestp[mf * 4 + r] = umax2(bestp[mf * 4 + r],
                                          umax2(umax2(c[0], c[1]), umax2(c[2], c[3])));
            }
    }

    // reduce over ln (16 lanes per g-group share positions, hold disjoint codes)
    #pragma unroll
    for (int off = 1; off < 16; off <<= 1) {
        #pragma unroll
        for (int s = 0; s < 32; ++s)
            bestp[s] = umax2(bestp[s], (unsigned)__shfl_xor((int)bestp[s], off));
    }

    // merge 4 waves via LDS atomicMax, then decode
    __syncthreads();                                   // xs reads done
    unsigned* merged = (unsigned*)xs;
    if (tid < 128) merged[tid] = 0u;
    __syncthreads();
    if (ln == 0) {
        #pragma unroll
        for (int mf = 0; mf < 8; ++mf)
            #pragma unroll
            for (int r = 0; r < 4; ++r)
                atomicMax(&merged[mf * 16 + g * 4 + r], bestp[mf * 4 + r]);
    }
    __syncthreads();
    if (tid < 128) idx_out[n0 + tid] = 1023 - (int)(merged[tid] & 1023u);
}

// ---------------------------------------------------------------------------
// Kernel 3: gather + quantize + fused (x-q)^2 partials. float4 over p.
__global__ __launch_bounds__(256) void quantize_kernel(
        const float* __restrict__ x, const float* __restrict__ cb,
        const int* __restrict__ idx, float* __restrict__ out,
        float* __restrict__ partial) {
    const int blk = blockIdx.x;
    const int b  = blk >> 2;
    const int d0 = (blk & 3) * 64;
    const int tid = threadIdx.x;
    const int4 ci = *reinterpret_cast<const int4*>(&idx[b * HW + tid * 4]);
    const int cia[4] = {ci.x, ci.y, ci.z, ci.w};
    const size_t xbase = (size_t)b * (DIM * HW) + tid * 4;

    float s = 0.0f;
    #pragma unroll 4
    for (int dq = 0; dq < 16; ++dq) {
        const int dd = d0 + dq * 4;
        float4 xv[4], cv[4];
        #pragma unroll
        for (int j = 0; j < 4; ++j)
            xv[j] = *reinterpret_cast<const float4*>(&x[xbase + (size_t)(dd + j) * HW]);
        #pragma unroll
        for (int e = 0; e < 4; ++e)
            cv[e] = *reinterpret_cast<const float4*>(&cb[(size_t)cia[e] * DIM + dd]);
        #pragma unroll
        for (int j = 0; j < 4; ++j) {
            const float q0 = (&cv[0].x)[j], q1 = (&cv[1].x)[j],
                        q2 = (&cv[2].x)[j], q3 = (&cv[3].x)[j];
            float4 ov = {q0, q1, q2, q3};
            *reinterpret_cast<float4*>(&out[xbase + (size_t)(dd + j) * HW]) = ov;
            const float e0 = xv[j].x - q0, e1 = xv[j].y - q1,
                        e2 = xv[j].z - q2, e3 = xv[j].w - q3;
            s = fmaf(e0, e0, s); s = fmaf(e1, e1, s);
            s = fmaf(e2, e2, s); s = fmaf(e3, e3, s);
        }
    }
    #pragma unroll
    for (int off = 32; off; off >>= 1) s += __shfl_xor(s, off);
    __shared__ float wsum[4];
    if ((tid & 63) == 0) wsum[tid >> 6] = s;
    __syncthreads();
    if (tid == 0) partial[blk] = wsum[0] + wsum[1] + wsum[2] + wsum[3];
}

// ---------------------------------------------------------------------------
__global__ void finalize_kernel(const float* __restrict__ partial, float* __restrict__ out_loss) {
    float s = (threadIdx.x < 256) ? partial[threadIdx.x] : 0.0f;
    #pragma unroll
    for (int off = 32; off; off >>= 1) s += __shfl_xor(s, off);
    __shared__ float wsum[4];
    if ((threadIdx.x & 63) == 0) wsum[threadIdx.x >> 6] = s;
    __syncthreads();
    if (threadIdx.x == 0)
        out_loss[0] = 1.25f * (wsum[0] + wsum[1] + wsum[2] + wsum[3]) / (float)NTOT;
}

// ---------------------------------------------------------------------------
extern "C" void kernel_launch(void* const* d_in, const int* in_sizes, int n_in,
                              void* d_out, int out_size, void* d_ws, size_t ws_size,
                              hipStream_t stream) {
    const float* x  = (const float*)d_in[0];   // [64,256,32,32]
    const float* cb = (const float*)d_in[1];   // [1024,256]
    float* out = (float*)d_out;                // [16777216] + [1 loss]

    // xt (32 MB) + cbt (512 KB) live in d_out; quantize overwrites later.
    unsigned short* xt  = (unsigned short*)d_out;
    unsigned short* cbt = xt + (size_t)N_POS * DIM;
    // ws: idx[65536] ints | partial[256] f32 | cnorm[1024] f32
    int*   idx     = (int*)d_ws;
    float* partial = (float*)((char*)d_ws + 262144);
    float* cnorm   = (float*)((char*)d_ws + 262144 + 4096);

    cbprep_kernel   <<<dim3(256),  dim3(256), 0, stream>>>(cb, cbt, cnorm);
    transpose_kernel<<<dim3(1024), dim3(256), 0, stream>>>(x, xt);
    score_kernel    <<<dim3(512),  dim3(256), 0, stream>>>(xt, cbt, cnorm, idx);
    quantize_kernel <<<dim3(256),  dim3(256), 0, stream>>>(x, cb, idx, out, partial);
    finalize_kernel <<<dim3(1),    dim3(256), 0, stream>>>(partial, out + NTOT);
}